// Round 1
// baseline (240.296 us; speedup 1.0000x reference)
//
#include <hip/hip_runtime.h>
#include <math.h>

#define SS 1024
#define NC 8
#define BWD 170
#define THRESH 1e-4f

typedef unsigned long long ull;

__device__ __forceinline__ float2 cmul(float2 a, float2 b) {
    return make_float2(a.x * b.x - a.y * b.y, a.x * b.y + a.y * b.x);
}

// ---------------------------------------------------------------------------
// XOR bank swizzle, bijection on [0,1024) float2 slots. Every exchange
// pattern below (write fixed-c across lanes, read strided) lands exactly
// 4 lanes per bank-pair = the structural floor for b64 on 32 banks.
// ---------------------------------------------------------------------------
#define XS(a) ((a) ^ (((a) >> 4) & 15))

template <int DIR>
__device__ __forceinline__ void bfly4(const float2 v[4], float2 r[4]) {
    float2 a = v[0], b = v[1], c = v[2], d = v[3];
    float2 apc = make_float2(a.x + c.x, a.y + c.y);
    float2 amc = make_float2(a.x - c.x, a.y - c.y);
    float2 bpd = make_float2(b.x + d.x, b.y + d.y);
    float2 jb  = make_float2(-(b.y - d.y), b.x - d.x);   // i*(b-d)
    r[0] = make_float2(apc.x + bpd.x, apc.y + bpd.y);
    r[2] = make_float2(apc.x - bpd.x, apc.y - bpd.y);
    if (DIR == -1) {
        r[1] = make_float2(amc.x - jb.x, amc.y - jb.y);
        r[3] = make_float2(amc.x + jb.x, amc.y + jb.y);
    } else {
        r[1] = make_float2(amc.x + jb.x, amc.y + jb.y);
        r[3] = make_float2(amc.x - jb.x, amc.y - jb.y);
    }
}

// multiply by exp(DIR*2pi*i*theta) given (cos theta, sin theta) constants
template <int DIR>
__device__ __forceinline__ float2 wc(float2 a, float cr, float si) {
    float s = (DIR == -1) ? -si : si;
    return make_float2(a.x * cr - a.y * s, a.x * s + a.y * cr);
}

// ---------------------------------------------------------------------------
// Lane-local 16-pt DFT (radix-4 x radix-4, W16 twiddles are compile-time
// constants) followed by u[c] *= exp(DIR*2pi*i*c*rev). The rev-twiddles come
// from ONE hw sincos + a depth<=4 squaring/product chain (error ~4 ulp).
// in: u[b]; out: u[c] = sum_b u_in[b]*exp(DIR*2pi*i*(b*c/16 + c*rev)).
// ---------------------------------------------------------------------------
template <int DIR>
__device__ __forceinline__ void dft16_tw(float2 u[16], float rev) {
    float2 t[4][4];
    #pragma unroll
    for (int a = 0; a < 4; ++a) {
        float2 in[4] = { u[a], u[a + 4], u[a + 8], u[a + 12] };
        bfly4<DIR>(in, t[a]);
    }
    const float C1 = 0.923879532511287f, S1 = 0.382683432365090f;
    const float C2 = 0.707106781186548f;
    t[1][1] = wc<DIR>(t[1][1], C1, S1);        // W16^1
    t[1][2] = wc<DIR>(t[1][2], C2, C2);        // W16^2
    t[1][3] = wc<DIR>(t[1][3], S1, C1);        // W16^3
    t[2][1] = wc<DIR>(t[2][1], C2, C2);        // W16^2
    t[2][2] = (DIR == -1) ? make_float2(t[2][2].y, -t[2][2].x)    // W16^4 = -i*DIR... (0, DIR)
                          : make_float2(-t[2][2].y, t[2][2].x);
    t[2][3] = wc<DIR>(t[2][3], -C2, C2);       // W16^6
    t[3][1] = wc<DIR>(t[3][1], S1, C1);        // W16^3
    t[3][2] = wc<DIR>(t[3][2], -C2, C2);       // W16^6
    t[3][3] = wc<DIR>(t[3][3], -C1, -S1);      // W16^9
    #pragma unroll
    for (int ci = 0; ci < 4; ++ci) {
        float2 in[4] = { t[0][ci], t[1][ci], t[2][ci], t[3][ci] };
        float2 s[4];
        bfly4<DIR>(in, s);
        u[ci] = s[0]; u[ci + 4] = s[1]; u[ci + 8] = s[2]; u[ci + 12] = s[3];
    }
    float cs = __builtin_amdgcn_cosf(rev);
    float sn = __builtin_amdgcn_sinf(rev);
    float2 w1 = make_float2(cs, (float)DIR * sn);
    float2 w2 = cmul(w1, w1);
    float2 w3 = cmul(w2, w1);
    float2 w4 = cmul(w2, w2);
    float2 w8 = cmul(w4, w4);
    u[1]  = cmul(u[1], w1);
    u[2]  = cmul(u[2], w2);
    u[3]  = cmul(u[3], w3);
    u[4]  = cmul(u[4], w4);
    u[5]  = cmul(u[5], cmul(w4, w1));
    u[6]  = cmul(u[6], cmul(w4, w2));
    u[7]  = cmul(u[7], cmul(w4, w3));
    u[8]  = cmul(u[8], w8);
    u[9]  = cmul(u[9], cmul(w8, w1));
    u[10] = cmul(u[10], cmul(w8, w2));
    u[11] = cmul(u[11], cmul(w8, w3));
    u[12] = cmul(u[12], cmul(w8, w4));
    u[13] = cmul(u[13], cmul(w8, cmul(w4, w1)));
    u[14] = cmul(u[14], cmul(w8, cmul(w4, w2)));
    u[15] = cmul(u[15], cmul(w8, cmul(w4, w3)));
}

// ---------------------------------------------------------------------------
// PER-WAVE 1024-pt FFT: 64 lanes x 16 elements, decomposition 16x16x4.
// On entry v[b] = x[l + 64b]; on exit v[j] = FFT(x)[l + 64j] (natural order).
// X = this wave's PRIVATE 1024-float2 LDS region. Two LDS exchanges, ZERO
// barriers: wave-internal lockstep + in-order DS pipe; explicit lgkmcnt(0)
// fences pin the write->read / read->write ordering at both compiler & HW
// level. Index chain verified via impulse response: out[k]=W_1024^k for
// x = delta[n-1], k = c + 16c' + 256d'.
// ---------------------------------------------------------------------------
template <int DIR>
__device__ __forceinline__ void fft1024_wave(float2 v[16], float2* X, int l) {
    // P1: 16-pt DFT over b + twiddle W_1024^{l*c}
    dft16_tw<DIR>(v, (float)l * (1.0f / 1024.0f));
    int base = l << 4;
    #pragma unroll
    for (int cc = 0; cc < 16; ++cc) X[XS(base + cc)] = v[cc];
    asm volatile("s_waitcnt lgkmcnt(0)" ::: "memory");
    // Exchange 1: lane (a'=l&3, c=l>>2) gathers Z[a'+4b'][c]
    int a_ = l & 3, cr = l >> 2;
    #pragma unroll
    for (int b = 0; b < 16; ++b)
        v[b] = X[XS(((a_ + (b << 2)) << 4) + cr)];
    asm volatile("s_waitcnt lgkmcnt(0)" ::: "memory");
    // P2: 16-pt DFT over b' + twiddle W_64^{a'*c'}
    dft16_tw<DIR>(v, (float)a_ * (1.0f / 64.0f));
    #pragma unroll
    for (int cc = 0; cc < 16; ++cc) X[XS(base + cc)] = v[cc];
    asm volatile("s_waitcnt lgkmcnt(0)" ::: "memory");
    // Exchange 2: lane (c=l&15, c'l=l>>4) gathers Z'[c][a2][c'l+4c'h]
    int c2 = l & 15, cl2 = l >> 4;
    float2 q[16];
    #pragma unroll
    for (int a2 = 0; a2 < 4; ++a2)
        #pragma unroll
        for (int chh = 0; chh < 4; ++chh)
            q[(a2 << 2) + chh] =
                X[XS(((a2 + (c2 << 2)) << 4) + cl2 + (chh << 2))];
    asm volatile("s_waitcnt lgkmcnt(0)" ::: "memory");
    // P3: twiddle-free radix-4 over a2; v[c'h + 4d'] = out element l + 64j
    #pragma unroll
    for (int chh = 0; chh < 4; ++chh) {
        float2 in[4] = { q[chh], q[4 + chh], q[8 + chh], q[12 + chh] };
        float2 r[4];
        bfly4<DIR>(in, r);
        v[chh] = r[0]; v[chh + 4] = r[1]; v[chh + 8] = r[2]; v[chh + 12] = r[3];
    }
}

// ---------------------------------------------------------------------------
// Fused blur + alpha blend + pack + forward row FFT. Block = 4 rows, one
// PER WAVE (fully independent -> zero __syncthreads in the kernel). Lane l
// owns 16 contiguous columns: V-blur accumulated in registers over a 24-col
// aligned window, H-blur in registers, blend, handoff to the wave's private
// LDS region (XS layout), per-wave FFT, coalesced register store.
// XCD band swizzle keeps the 7-row V-blur halo in one XCD's L2 (as before).
// ---------------------------------------------------------------------------
__global__ __launch_bounds__(256) void blur_fft_kernel(
        const float* __restrict__ lms, const float* __restrict__ fuse,
        float2* __restrict__ Zf) {
    __shared__ float2 xch[4][1024];     // 32 KB: one 8 KB region per wave
    int tid = threadIdx.x;
    int wv = tid >> 6, l = tid & 63;
    int g = blockIdx.x;
    int c = g >> 8;                                 // 2048 blocks: 8ch x 256
    int rg = (g & 7) * 32 + ((g >> 3) & 31);        // XCD band swizzle
    int y = (rg << 2) + wv;
    const float* L = lms + ((size_t)c << 20);
    const float* F = fuse + ((size_t)c << 20);
    float2* X = xch[wv];

    // Gaussian weights (sigma=1, ks=7) - constant-folded
    double e1 = exp(-0.5), e2 = exp(-2.0), e3 = exp(-4.5);
    double sm = 1.0 + 2.0 * (e1 + e2 + e3);
    float w[7] = { (float)(e3 / sm), (float)(e2 / sm), (float)(e1 / sm),
                   (float)(1.0 / sm),
                   (float)(e1 / sm), (float)(e2 / sm), (float)(e3 / sm) };

    bool rowInt = (y >= BWD) && (y <= SS - 1 - BWD);
    // lanes whose 16 cols lie fully in the alpha==1 interior: skip blur
    bool skipB = rowInt && (l >= 11) && (l <= 52);
    int gyv = (y < BWD) ? y : ((SS - 1 - y) < BWD ? (SS - 1 - y) : -1);

    if (skipB) {
        #pragma unroll
        for (int m = 0; m < 4; ++m) {
            float4 cl = *(const float4*)&L[((size_t)y << 10) + (l << 4) + (m << 2)];
            float4 cf = *(const float4*)&F[((size_t)y << 10) + (l << 4) + (m << 2)];
            #pragma unroll
            for (int n = 0; n < 4; ++n)
                X[XS((l << 4) + (m << 2) + n)] =
                    make_float2((&cl.x)[n], (&cf.x)[n]);
        }
    } else {
        // V-blur into a 24-col aligned register window (cols 16l-4 .. 16l+19)
        float accL[24], accF[24];
        #pragma unroll
        for (int j = 0; j < 24; ++j) { accL[j] = 0.f; accF[j] = 0.f; }
        #pragma unroll
        for (int r = 0; r < 7; ++r) {
            int gy = y - 3 + r;
            if (gy < 0 || gy >= SS) continue;       // zero-pad rows
            const float* Lr = L + ((size_t)gy << 10);
            const float* Fr = F + ((size_t)gy << 10);
            float wr = w[r];
            #pragma unroll
            for (int q = 0; q < 6; ++q) {
                int f = (l << 2) - 1 + q;           // float4 index
                if (f >= 0 && f < 256) {            // zero-pad cols
                    float4 vl = *(const float4*)&Lr[f << 2];
                    float4 vf = *(const float4*)&Fr[f << 2];
                    accL[(q << 2) + 0] += wr * vl.x; accF[(q << 2) + 0] += wr * vf.x;
                    accL[(q << 2) + 1] += wr * vl.y; accF[(q << 2) + 1] += wr * vf.y;
                    accL[(q << 2) + 2] += wr * vl.z; accF[(q << 2) + 2] += wr * vf.z;
                    accL[(q << 2) + 3] += wr * vl.w; accF[(q << 2) + 3] += wr * vf.w;
                }
            }
        }
        // H-blur + alpha blend (center reloaded: L1/L2-hot from r==3 pass)
        #pragma unroll
        for (int m = 0; m < 4; ++m) {
            float4 cl = *(const float4*)&L[((size_t)y << 10) + (l << 4) + (m << 2)];
            float4 cf = *(const float4*)&F[((size_t)y << 10) + (l << 4) + (m << 2)];
            #pragma unroll
            for (int n = 0; n < 4; ++n) {
                int k = (m << 2) + n;
                float bl = 0.f, bf = 0.f;
                #pragma unroll
                for (int j = 0; j < 7; ++j) {       // col 16l+k-3+j -> acc[k+1+j]
                    bl += w[j] * accL[k + 1 + j];
                    bf += w[j] * accF[k + 1 + j];
                }
                int x = (l << 4) + k;
                int gx = (x < BWD) ? x : ((SS - 1 - x) < BWD ? (SS - 1 - x) : -1);
                int mm = gyv > gx ? gyv : gx;
                float a = (mm >= 0) ? (float)mm * (1.0f / BWD) : 1.0f;
                X[XS((l << 4) + k)] = make_float2(
                    a * (&cl.x)[n] + (1.0f - a) * bl,
                    a * (&cf.x)[n] + (1.0f - a) * bf);
            }
        }
    }
    asm volatile("s_waitcnt lgkmcnt(0)" ::: "memory");
    float2 v[16];
    #pragma unroll
    for (int b = 0; b < 16; ++b) v[b] = X[XS(l + (b << 6))];
    fft1024_wave<-1>(v, X, l);
    float2* Zrow = Zf + (((size_t)c << 20) + ((size_t)y << 10));
    #pragma unroll
    for (int j = 0; j < 16; ++j) Zrow[l + (j << 6)] = v[j];
}

// ---------------------------------------------------------------------------
// Fused second forward FFT + Wiener + first inverse FFT (along ky).
// Block owns a conjugate row pair (u, 1024-u) for channel pair p. The 4
// forward FFTs run in PARALLEL, one per wave (combo = wave = rowIdx*2+ch);
// results staged in XS layout. Waves 0/1 compute Wiener for their row at
// their own FFT-input frequencies (vv = l+64j), then run the 2 inverse FFTs.
// Only TWO barriers in the whole kernel (vs ~30 before).
// ---------------------------------------------------------------------------
__global__ __launch_bounds__(256) void fft2_wiener_kernel(
        const float2* __restrict__ Z, float2* __restrict__ Wb) {
    __shared__ float2 xch[4][1024];
    int tid = threadIdx.x;
    int wv = tid >> 6, l = tid & 63;
    int p = blockIdx.x >> 9;          // channel pair 0..3
    int i = blockIdx.x & 511;
    bool selfp = (i == 0);
    int row0 = selfp ? 0 : i;
    int row1 = selfp ? 512 : 1024 - i;
    int ch = wv & 1;
    int myrow = (wv & 2) ? row1 : row0;
    const float2* g0 = Z + (((size_t)(2 * p + ch) << 20) + ((size_t)myrow << 10));
    float2 v[16];
    #pragma unroll
    for (int b = 0; b < 16; ++b) v[b] = g0[l + (b << 6)];
    fft1024_wave<-1>(v, xch[wv], l);
    #pragma unroll
    for (int j = 0; j < 16; ++j) xch[wv][XS(l + (j << 6))] = v[j];
    __syncthreads();                  // all 4 forward results visible

    float2 gi[16];
    if (wv < 2) {
        int u = wv ? row1 : row0;
        int po = selfp ? wv : (1 - wv);
        float cu = __builtin_amdgcn_cosf((float)u * (1.0f / 1024.0f));
        float c2u = 2.0f * cu * cu - 1.0f;
        float hu = 2.0f + 2.0f * cu;
        #pragma unroll
        for (int j = 0; j < 16; ++j) {
            int vv = l + (j << 6);
            int vn = (1024 - vv) & 1023;
            float cv = __builtin_amdgcn_cosf((float)vv * (1.0f / 1024.0f));
            float c2v = 2.0f * cv * cv - 1.0f;
            float hv = 2.0f + 2.0f * cv;
            float grad = (2.0f - 2.0f * c2v) * hu * hu +
                         (2.0f - 2.0f * c2u) * hv * hv;
            float regs = 5.0f + 5.0f * grad;
            float G0x, G0y, G1x, G1y;
            #pragma unroll
            for (int cc = 0; cc < 2; ++cc) {
                float2 a = xch[wv * 2 + cc][XS(vv)];
                float2 b = xch[po * 2 + cc][XS(vn)];
                float Lx = 0.5f * (a.x + b.x), Ly = 0.5f * (a.y - b.y);
                float Fx = 0.5f * (a.y + b.y), Fy = -0.5f * (a.x - b.x);
                float inv = 1.0f / (Fx * Fx + Fy * Fy + regs);
                float nx = (Fx * Lx + Fy * Ly) * inv;   // conj(F)*L
                float ny = (Fx * Ly - Fy * Lx) * inv;
                if (cc == 0) { G0x = nx; G0y = ny; } else { G1x = nx; G1y = ny; }
            }
            gi[j] = make_float2(G0x - G1y, G0y + G1x);
        }
    }
    __syncthreads();                  // all xch reads done; buffers reusable

    if (wv < 2) {
        fft1024_wave<1>(gi, xch[wv], l);
        const float isc = 1.0f / 1024.0f;
        int orow = wv ? row1 : row0;
        float2* go = Wb + (((size_t)p << 20) + ((size_t)orow << 10));
        #pragma unroll
        for (int j = 0; j < 16; ++j)
            go[l + (j << 6)] = make_float2(gi[j].x * isc, gi[j].y * isc);
    }
}

// ---------------------------------------------------------------------------
// Final inverse pass: block = 4 rows, one per wave. Per-wave FFT, fused
// 1/N scale + fftshift + threshold + split + WAVE-LOCAL argmax (shuffle
// reduce over 64 lanes, lane 0 writes the private bm slot). Zero barriers.
// ---------------------------------------------------------------------------
__global__ __launch_bounds__(256) void ifft_final_kernel(
        const float2* __restrict__ Wd, float* __restrict__ psf,
        ull* __restrict__ bm) {
    __shared__ float2 xch[4][1024];
    int tid = threadIdx.x;
    int wv = tid >> 6, l = tid & 63;
    int R = blockIdx.x * 4 + wv;
    const float2* g = Wd + ((size_t)R << 10);
    float2 v[16];
    #pragma unroll
    for (int b = 0; b < 16; ++b) v[b] = g[l + (b << 6)];
    fft1024_wave<1>(v, xch[wv], l);

    int p = R >> 10;
    int y = R & 1023;
    int oy = (y + 512) & 1023;
    float* p0 = psf + (((size_t)(2 * p) << 20) + ((size_t)oy << 10));
    float* p1 = p0 + (1u << 20);
    const float sc = 1.0f / 1024.0f;
    ull e0 = 0, e1 = 0;
    #pragma unroll
    for (int j = 0; j < 16; ++j) {
        int k = l + (j << 6);
        float re = v[j].x * sc; re = (re < THRESH) ? 0.0f : re;
        float im = v[j].y * sc; im = (im < THRESH) ? 0.0f : im;
        int ox = (k + 512) & 1023;
        p0[ox] = re;
        p1[ox] = im;
        unsigned int idx = ((unsigned int)oy << 10) | (unsigned int)ox;
        ull c0 = ((ull)__float_as_uint(re) << 32) | (ull)(0xFFFFFFFFu - idx);
        ull c1 = ((ull)__float_as_uint(im) << 32) | (ull)(0xFFFFFFFFu - idx);
        e0 = c0 > e0 ? c0 : e0;
        e1 = c1 > e1 ? c1 : e1;
    }
    #pragma unroll
    for (int off = 32; off > 0; off >>= 1) {
        ull o0 = __shfl_down(e0, off);
        ull o1 = __shfl_down(e1, off);
        e0 = o0 > e0 ? o0 : e0;
        e1 = o1 > e1 ? o1 : e1;
    }
    if (l == 0) {
        bm[((size_t)(2 * p) << 10) + y] = e0;
        bm[((size_t)(2 * p + 1) << 10) + y] = e1;
    }
}

// ---------------------------------------------------------------------------
// In-place square transpose, 32x32 float2 tile pairs, float4-vectorized
// global I/O (2 float2 per lane), per plane (grid.y = plane).
// ---------------------------------------------------------------------------
__global__ __launch_bounds__(256) void transpose_kernel(float2* __restrict__ A) {
    __shared__ float2 ta[32][33];
    __shared__ float2 tb[32][33];
    float2* P = A + ((size_t)blockIdx.y << 20);
    int r = blockIdx.x, bi = 0;
    while (r >= 32 - bi) { r -= 32 - bi; ++bi; }
    int bj = bi + r;
    int tx = threadIdx.x & 15;     // float4 index (covers 2 float2 cols)
    int ty = threadIdx.x >> 4;     // 16 rows per iteration
    #pragma unroll
    for (int yy0 = 0; yy0 < 32; yy0 += 16) {
        int yy = yy0 + ty;
        float4 va = *(const float4*)&P[(size_t)(bi * 32 + yy) * SS + bj * 32 + 2 * tx];
        float4 vb = *(const float4*)&P[(size_t)(bj * 32 + yy) * SS + bi * 32 + 2 * tx];
        ta[yy][2 * tx]     = make_float2(va.x, va.y);
        ta[yy][2 * tx + 1] = make_float2(va.z, va.w);
        tb[yy][2 * tx]     = make_float2(vb.x, vb.y);
        tb[yy][2 * tx + 1] = make_float2(vb.z, vb.w);
    }
    __syncthreads();
    #pragma unroll
    for (int yy0 = 0; yy0 < 32; yy0 += 16) {
        int yy = yy0 + ty;
        float2 a0 = tb[2 * tx][yy], a1 = tb[2 * tx + 1][yy];
        *(float4*)&P[(size_t)(bi * 32 + yy) * SS + bj * 32 + 2 * tx] =
            make_float4(a0.x, a0.y, a1.x, a1.y);
        float2 b0 = ta[2 * tx][yy], b1 = ta[2 * tx + 1][yy];
        *(float4*)&P[(size_t)(bj * 32 + yy) * SS + bi * 32 + 2 * tx] =
            make_float4(b0.x, b0.y, b1.x, b1.y);
    }
}

// ---------------------------------------------------------------------------
// Per-channel argmax finish (reduce 1024 per-block maxima) + crop 41x41
// (dynamic_slice clamp semantics) + normalize. One block per channel.
// ---------------------------------------------------------------------------
__global__ __launch_bounds__(256) void crop_kernel(
        const float* __restrict__ psf, const ull* __restrict__ bm,
        float* __restrict__ out) {
    int c = blockIdx.x;
    __shared__ ull rmax[256];
    __shared__ float red[256];
    int tid = threadIdx.x;
    ull e = 0;
    for (int i = tid; i < 1024; i += 256) {
        ull v = bm[((size_t)c << 10) + i];
        e = v > e ? v : e;
    }
    rmax[tid] = e;
    __syncthreads();
    for (int s2 = 128; s2 > 0; s2 >>= 1) {
        if (tid < s2) { ull a = rmax[tid], b = rmax[tid + s2]; rmax[tid] = a > b ? a : b; }
        __syncthreads();
    }
    unsigned int bidx = 0xFFFFFFFFu - (unsigned int)(rmax[0] & 0xFFFFFFFFull);
    int row = (int)(bidx >> 10), col = (int)(bidx & 1023);
    int r0 = row - 20; if (r0 < 0) r0 = 0; if (r0 > SS - 41) r0 = SS - 41;
    int c0 = col - 20; if (c0 < 0) c0 = 0; if (c0 > SS - 41) c0 = SS - 41;
    const float* p = psf + ((size_t)c << 20);
    float local = 0.0f;
    for (int i = tid; i < 1681; i += 256) {
        int rr = i / 41, cc = i - rr * 41;
        local += p[(size_t)(r0 + rr) * SS + c0 + cc];
    }
    red[tid] = local;
    __syncthreads();
    for (int s2 = 128; s2 > 0; s2 >>= 1) {
        if (tid < s2) red[tid] += red[tid + s2];
        __syncthreads();
    }
    float inv = 1.0f / red[0];
    for (int i = tid; i < 1681; i += 256) {
        int rr = i / 41, cc = i - rr * 41;
        out[c * 1681 + i] = p[(size_t)(r0 + rr) * SS + c0 + cc] * inv;
    }
}

// ---------------------------------------------------------------------------
extern "C" void kernel_launch(void* const* d_in, const int* in_sizes, int n_in,
                              void* d_out, int out_size, void* d_ws,
                              size_t ws_size, hipStream_t stream) {
    const float* lms = (const float*)d_in[0];
    const float* fuse = (const float*)d_in[1];
    char* ws = (char*)d_ws;
    float2* Zf = (float2*)ws;                                   // 64 MB: 8 planes
    float2* Wb = (float2*)(ws + ((size_t)64 << 20));            // 32 MB: 4 planes
    float* psf = (float*)ws;                                    // 32 MB, reuses Zf
    ull* bm = (ull*)(ws + ((size_t)33 << 20));                  // 64 KB, dead Zf region
    float* outp = (float*)d_out;

    // 1. fused blur + pack + forward row-FFT -> Zf[c][y][kx]  (4 rows/block)
    blur_fft_kernel<<<2048, 256, 0, stream>>>(lms, fuse, Zf);
    // 2. transpose -> Zf[c][kx][y]
    transpose_kernel<<<dim3(528, 8), 256, 0, stream>>>(Zf);
    // 3. fused col-FFT + Wiener + inverse-ky-FFT -> Wb[p][kx][y]
    fft2_wiener_kernel<<<2048, 256, 0, stream>>>(Zf, Wb);
    // 4. transpose -> Wb[p][y][kx]
    transpose_kernel<<<dim3(528, 4), 256, 0, stream>>>(Wb);
    // 5. inverse kx-FFT + shift/threshold/split/wave-argmax (4 rows/block)
    ifft_final_kernel<<<1024, 256, 0, stream>>>(Wb, psf, bm);
    // 6. argmax finish + crop/normalize
    crop_kernel<<<8, 256, 0, stream>>>(psf, bm, outp);
}

// Round 2
// 207.654 us; speedup vs baseline: 1.1572x; 1.1572x over previous
//
#include <hip/hip_runtime.h>
#include <math.h>

#define SS 1024
#define NC 8
#define BWD 170
#define THRESH 1e-4f

typedef unsigned long long ull;

__device__ __forceinline__ float2 cmul(float2 a, float2 b) {
    return make_float2(a.x * b.x - a.y * b.y, a.x * b.y + a.y * b.x);
}

// ---------------------------------------------------------------------------
// XOR bank swizzle for FFT LDS buffers: bijection on [0,1024), mixes bits 4-7
// into bits 0-3 so every Stockham write stage hits 16 distinct bank-pairs
// while stride-1 reads stay conflict-free.
// ---------------------------------------------------------------------------
#define XS(a) ((a) ^ (((a) >> 4) & 15))

template <int DIR>
__device__ __forceinline__ void bfly4(const float2 v[4], float2 r[4]) {
    float2 a = v[0], b = v[1], c = v[2], d = v[3];
    float2 apc = make_float2(a.x + c.x, a.y + c.y);
    float2 amc = make_float2(a.x - c.x, a.y - c.y);
    float2 bpd = make_float2(b.x + d.x, b.y + d.y);
    float2 jb  = make_float2(-(b.y - d.y), b.x - d.x);   // i*(b-d)
    r[0] = make_float2(apc.x + bpd.x, apc.y + bpd.y);
    r[2] = make_float2(apc.x - bpd.x, apc.y - bpd.y);
    if (DIR == -1) {
        r[1] = make_float2(amc.x - jb.x, amc.y - jb.y);
        r[3] = make_float2(amc.x + jb.x, amc.y + jb.y);
    } else {
        r[1] = make_float2(amc.x + jb.x, amc.y + jb.y);
        r[3] = make_float2(amc.x - jb.x, amc.y - jb.y);
    }
}

// ---------------------------------------------------------------------------
// 1024-pt Stockham radix-4, register-resident ends, INLINE twiddles.
// w1 = exp(DIR*2pi*i*k/1024) via HW sincos (revolutions); w2 = w1^2,
// w3 = w1*w2. Stages 0-3 via LDS (XS swizzle, 1 barrier each); stage 4
// (s=256, k=0, twiddle-free, thread-local) in registers.
// On entry v[m] holds element (tid+256m); on exit v[r] = element tid+256r.
// ---------------------------------------------------------------------------
template <int DIR>
__device__ __forceinline__ void fft1024_reg(float2 v[4], float2* A, float2* B,
                                            int tid) {
    float2* dst = A;
    float2* alt = B;
    #pragma unroll
    for (int t = 0; t < 4; ++t) {
        int s = 1 << (2 * t);
        int k = tid & ~(s - 1);
        float2 r[4];
        bfly4<DIR>(v, r);
        float rev = (float)k * (1.0f / 1024.0f);
        float2 w1 = make_float2(__builtin_amdgcn_cosf(rev),
                                (float)DIR * __builtin_amdgcn_sinf(rev));
        float2 w2 = cmul(w1, w1);
        float2 w3 = cmul(w2, w1);
        int base = tid + 3 * k;
        dst[XS(base)]         = r[0];
        dst[XS(base + s)]     = cmul(r[1], w1);
        dst[XS(base + 2 * s)] = cmul(r[2], w2);
        dst[XS(base + 3 * s)] = cmul(r[3], w3);
        __syncthreads();
        v[0] = dst[XS(tid)];
        v[1] = dst[XS(tid + 256)];
        v[2] = dst[XS(tid + 512)];
        v[3] = dst[XS(tid + 768)];
        float2* tmp = dst; dst = alt; alt = tmp;
    }
    float2 r[4];
    bfly4<DIR>(v, r);   // stage 4: twiddle-free, thread-local
    v[0] = r[0]; v[1] = r[1]; v[2] = r[2]; v[3] = r[3];
}

// LDS padding for the H-blur row buffers (float units, stride-4 reads)
#define PIDX(r) ((r) + ((r) >> 5))

// ---------------------------------------------------------------------------
// Fused blur + alpha blend + pack + forward row FFT. Block = (channel, row).
// XCD-band swizzle keeps the 7-row V-blur halo in one XCD's L2.
// V-blur in registers, H-blur via one LDS row, alpha blend,
// pack Z = lms_e + i*fuse_e into bufA (XS layout), FFT, store from registers.
// ---------------------------------------------------------------------------
__global__ __launch_bounds__(256) void blur_fft_kernel(
        const float* __restrict__ lms, const float* __restrict__ fuse,
        float2* __restrict__ Zf) {
    __shared__ float2 bufA[1024];      // handoff + FFT ping-pong partner
    __shared__ float2 smemB2[1068];    // aliases: rowl/rowf floats, FFT buffer
    float* rowl = (float*)smemB2;      // PIDX(col+3), col -3..1026
    float* rowf = rowl + 1068;
    int tid = threadIdx.x;
    int g = blockIdx.x;
    int c = g >> 10;
    int y = (g & 7) * 128 + ((g >> 3) & 127);   // XCD band swizzle
    const float* L = lms + ((size_t)c << 20);
    const float* F = fuse + ((size_t)c << 20);
    int x0 = tid << 2;

    // Gaussian weights (sigma=1, ks=7)
    double e1 = exp(-0.5), e2 = exp(-2.0), e3 = exp(-4.5);
    double sm = 1.0 + 2.0 * (e1 + e2 + e3);
    float w[7] = { (float)(e3 / sm), (float)(e2 / sm), (float)(e1 / sm),
                   (float)(1.0 / sm),
                   (float)(e1 / sm), (float)(e2 / sm), (float)(e3 / sm) };

    bool rowInt = (y >= BWD) && (y <= SS - 1 - BWD);
    bool skipLoads = rowInt && (tid >= 45) && (tid <= 210);
    bool doH = !rowInt || (tid <= 43) || (tid >= 212);

    float4 cl, cf;
    if (skipLoads) {
        cl = *(const float4*)&L[((size_t)y << 10) + x0];
        cf = *(const float4*)&F[((size_t)y << 10) + x0];
    } else {
        float4 lv[7], fv[7];
        #pragma unroll
        for (int r = 0; r < 7; ++r) {
            int gy = y - 3 + r;
            if (gy >= 0 && gy < SS) {
                lv[r] = *(const float4*)&L[((size_t)gy << 10) + x0];
                fv[r] = *(const float4*)&F[((size_t)gy << 10) + x0];
            } else {
                lv[r] = make_float4(0.f, 0.f, 0.f, 0.f);
                fv[r] = make_float4(0.f, 0.f, 0.f, 0.f);
            }
        }
        cl = lv[3]; cf = fv[3];
        #pragma unroll
        for (int j = 0; j < 4; ++j) {
            float a = 0.f, b = 0.f;
            #pragma unroll
            for (int r = 0; r < 7; ++r) {
                a += w[r] * (&lv[r].x)[j];
                b += w[r] * (&fv[r].x)[j];
            }
            rowl[PIDX(3 + x0 + j)] = a;
            rowf[PIDX(3 + x0 + j)] = b;
        }
    }
    if (tid < 3) {
        rowl[PIDX(tid)] = 0.f; rowf[PIDX(tid)] = 0.f;
        rowl[PIDX(1027 + tid)] = 0.f; rowf[PIDX(1027 + tid)] = 0.f;
    }
    __syncthreads();

    float bl[4] = {0.f, 0.f, 0.f, 0.f}, bf[4] = {0.f, 0.f, 0.f, 0.f};
    if (doH) {
        #pragma unroll
        for (int k = 0; k < 4; ++k) {
            float a = 0.f, b = 0.f;
            #pragma unroll
            for (int j = 0; j < 7; ++j) {
                a += w[j] * rowl[PIDX(x0 + k + j)];
                b += w[j] * rowf[PIDX(x0 + k + j)];
            }
            bl[k] = a; bf[k] = b;
        }
    }
    int gyv = (y < BWD) ? y : ((SS - 1 - y) < BWD ? (SS - 1 - y) : -1);
    #pragma unroll
    for (int k = 0; k < 4; ++k) {
        int x = x0 + k;
        int gx = (x < BWD) ? x : ((SS - 1 - x) < BWD ? (SS - 1 - x) : -1);
        int m = gyv > gx ? gyv : gx;
        float a = (m >= 0) ? (float)m / (float)BWD : 1.0f;
        bufA[XS(x)] = make_float2(a * (&cl.x)[k] + (1.0f - a) * bl[k],
                                  a * (&cf.x)[k] + (1.0f - a) * bf[k]);
    }
    __syncthreads();   // bufA handoff ready; rowl/rowf reads done

    float2 v[4];
    #pragma unroll
    for (int m = 0; m < 4; ++m) v[m] = bufA[XS(tid + (m << 8))];
    fft1024_reg<-1>(v, smemB2, bufA, tid);

    float2* Zrow = Zf + (((size_t)c << 20) + ((size_t)y << 10));
    #pragma unroll
    for (int r = 0; r < 4; ++r) Zrow[tid + (r << 8)] = v[r];
}

// ---------------------------------------------------------------------------
// Fused second forward FFT + Wiener + first inverse FFT (along ky).
// TRANSPOSE FUSED AWAY: reads COLUMN kx=u of Zf[c][y][kx] directly (lane
// stride 8KB, one 64B line per element). Zf (64MB) is L3-resident; the
// bijective bit-permutation i0 -> u puts the 8 blocks sharing each cache
// line (u-group of 8) on the SAME XCD (blockIdx%8 preserved), so each L2
// fetches each line once. One block owns a conjugate column pair
// (u, 1024-u) for a channel pair p: 4 forward FFTs, Wiener to registers,
// 2 inverse FFTs, store Wb[p][u][y] coalesced from registers.
// ---------------------------------------------------------------------------
__global__ __launch_bounds__(256) void fft2_wiener_kernel(
        const float2* __restrict__ Z, float2* __restrict__ Wb) {
    __shared__ float2 resbuf[4][1024];
    __shared__ float2 scratch[1024];
    int tid = threadIdx.x;
    int p = blockIdx.x >> 9;          // channel pair 0..3
    int i0 = blockIdx.x & 511;
    // bit-permutation: i0 bits[0:2] -> u bits[3:5], i0 bits[3:5] -> u bits[0:2]
    int i = ((i0 & 7) << 3) | ((i0 >> 3) & 7) | (i0 & ~63);
    int rows[2];
    rows[0] = (i == 0) ? 0 : i;
    rows[1] = (i == 0) ? 512 : 1024 - i;
    bool selfp = (i == 0);

    // combo = rowIdx*2 + ch; strided column loads (1 line/lane, L3-backed)
    float2 v[4], nv[4];
    {
        const float2* g0 = Z + (((size_t)(2 * p) << 20) + rows[0]);
        #pragma unroll
        for (int m = 0; m < 4; ++m)
            v[m] = g0[(size_t)(tid + (m << 8)) << 10];
    }
    #pragma unroll
    for (int combo = 0; combo < 4; ++combo) {
        if (combo < 3) {
            int nr = (combo + 1) >> 1, nc = (combo + 1) & 1;
            const float2* gn = Z + (((size_t)(2 * p + nc) << 20) + rows[nr]);
            #pragma unroll
            for (int m = 0; m < 4; ++m)
                nv[m] = gn[(size_t)(tid + (m << 8)) << 10];
        }
        fft1024_reg<-1>(v, scratch, resbuf[combo], tid);
        #pragma unroll
        for (int r = 0; r < 4; ++r)
            resbuf[combo][XS(tid + (r << 8))] = v[r];
        if (combo < 3) {
            #pragma unroll
            for (int m = 0; m < 4; ++m) v[m] = nv[m];
        }
    }
    __syncthreads();   // all forward results visible

    // Wiener to registers
    float2 gout[2][4];
    #pragma unroll
    for (int o = 0; o < 2; ++o) {
        int u = rows[o];
        int po = selfp ? o : (1 - o);      // partner row's slot base
        float cu = __builtin_amdgcn_cosf((float)u * (1.0f / 1024.0f));
        float c2u = 2.0f * cu * cu - 1.0f;
        float hu = 2.0f + 2.0f * cu;
        #pragma unroll
        for (int j = 0; j < 4; ++j) {
            int vv = tid + (j << 8);
            int vn = (1024 - vv) & 1023;
            float cv = __builtin_amdgcn_cosf((float)vv * (1.0f / 1024.0f));
            float c2v = 2.0f * cv * cv - 1.0f;
            float hv = 2.0f + 2.0f * cv;
            float grad = (2.0f - 2.0f * c2v) * hu * hu +
                         (2.0f - 2.0f * c2u) * hv * hv;
            float regs = 5.0f + 5.0f * grad;
            float G0x, G0y, G1x, G1y;
            #pragma unroll
            for (int c = 0; c < 2; ++c) {
                float2 a = resbuf[o * 2 + c][XS(vv)];
                float2 b = resbuf[po * 2 + c][XS(vn)];
                float Lx = 0.5f * (a.x + b.x), Ly = 0.5f * (a.y - b.y);
                float Fx = 0.5f * (a.y + b.y), Fy = -0.5f * (a.x - b.x);
                float inv = 1.0f / (Fx * Fx + Fy * Fy + regs);
                float nx = (Fx * Lx + Fy * Ly) * inv;   // conj(F)*L
                float ny = (Fx * Ly - Fy * Lx) * inv;
                if (c == 0) { G0x = nx; G0y = ny; } else { G1x = nx; G1y = ny; }
            }
            gout[o][j] = make_float2(G0x - G1y, G0y + G1x);
        }
    }
    __syncthreads();   // all resbuf reads complete; buffers reusable

    // inverse FFT along ky for both owned rows; store from registers
    const float isc = 1.0f / 1024.0f;
    #pragma unroll
    for (int o = 0; o < 2; ++o) {
        float2 iv[4];
        #pragma unroll
        for (int j = 0; j < 4; ++j) iv[j] = gout[o][j];   // already tid+256j
        fft1024_reg<1>(iv, scratch, resbuf[o], tid);
        float2* go = Wb + (((size_t)p << 20) + ((size_t)rows[o] << 10));
        #pragma unroll
        for (int r = 0; r < 4; ++r)
            go[tid + (r << 8)] = make_float2(iv[r].x * isc, iv[r].y * isc);
    }
}

// ---------------------------------------------------------------------------
// Final inverse pass: TRANSPOSE FUSED AWAY — reads column y of Wb[p][kx][y]
// (lane stride 8KB, one 64B line per element; Wb 32MB is L3-resident; the
// bit-permutation b -> y keeps the 8 line-sharing blocks on one XCD).
// Register row FFT, fused 1/N scale + fftshift + threshold + split into two
// real psf planes + per-block argmax to a PRIVATE slot bm[channel*1024+y].
// ---------------------------------------------------------------------------
__global__ __launch_bounds__(256) void ifft_final_kernel(
        const float2* __restrict__ Wd, float* __restrict__ psf,
        ull* __restrict__ bm) {
    __shared__ float2 bufA[1024];
    __shared__ float2 bufB[1024];
    __shared__ ull red0[4];
    __shared__ ull red1[4];
    int tid = threadIdx.x;
    int p = blockIdx.x >> 10;
    int b0 = blockIdx.x & 1023;
    // bit-permutation: b0 bits[0:2] -> y bits[3:5], b0 bits[3:5] -> y bits[0:2]
    int y = ((b0 & 7) << 3) | ((b0 >> 3) & 7) | (b0 & ~63);
    const float2* g = Wd + (((size_t)p << 20) + y);
    float2 v[4];
    #pragma unroll
    for (int m = 0; m < 4; ++m)
        v[m] = g[(size_t)(tid + (m << 8)) << 10];
    fft1024_reg<1>(v, bufA, bufB, tid);

    int oy = (y + 512) & 1023;
    float* p0 = psf + (((size_t)(2 * p) << 20) + ((size_t)oy << 10));
    float* p1 = p0 + (1u << 20);
    const float sc = 1.0f / 1024.0f;
    ull e0 = 0, e1 = 0;
    #pragma unroll
    for (int r = 0; r < 4; ++r) {
        int k = tid + (r << 8);
        float re = v[r].x * sc; re = (re < THRESH) ? 0.0f : re;
        float im = v[r].y * sc; im = (im < THRESH) ? 0.0f : im;
        int ox = (k + 512) & 1023;
        p0[ox] = re;
        p1[ox] = im;
        unsigned int idx = ((unsigned int)oy << 10) | (unsigned int)ox;
        ull c0 = ((ull)__float_as_uint(re) << 32) | (ull)(0xFFFFFFFFu - idx);
        ull c1 = ((ull)__float_as_uint(im) << 32) | (ull)(0xFFFFFFFFu - idx);
        e0 = c0 > e0 ? c0 : e0;
        e1 = c1 > e1 ? c1 : e1;
    }
    #pragma unroll
    for (int off = 32; off > 0; off >>= 1) {
        ull o0 = __shfl_down(e0, off);
        ull o1 = __shfl_down(e1, off);
        e0 = o0 > e0 ? o0 : e0;
        e1 = o1 > e1 ? o1 : e1;
    }
    if ((tid & 63) == 0) { red0[tid >> 6] = e0; red1[tid >> 6] = e1; }
    __syncthreads();
    if (tid == 0) {
        ull m0 = red0[0], m1 = red1[0];
        #pragma unroll
        for (int i2 = 1; i2 < 4; ++i2) {
            m0 = red0[i2] > m0 ? red0[i2] : m0;
            m1 = red1[i2] > m1 ? red1[i2] : m1;
        }
        bm[((size_t)(2 * p) << 10) + y] = m0;
        bm[((size_t)(2 * p + 1) << 10) + y] = m1;
    }
}

// ---------------------------------------------------------------------------
// Per-channel argmax finish (reduce 1024 per-block maxima) + crop 41x41
// (dynamic_slice clamp semantics) + normalize. One block per channel.
// ---------------------------------------------------------------------------
__global__ __launch_bounds__(256) void crop_kernel(
        const float* __restrict__ psf, const ull* __restrict__ bm,
        float* __restrict__ out) {
    int c = blockIdx.x;
    __shared__ ull rmax[256];
    __shared__ float red[256];
    int tid = threadIdx.x;
    ull e = 0;
    for (int i = tid; i < 1024; i += 256) {
        ull v = bm[((size_t)c << 10) + i];
        e = v > e ? v : e;
    }
    rmax[tid] = e;
    __syncthreads();
    for (int s2 = 128; s2 > 0; s2 >>= 1) {
        if (tid < s2) { ull a = rmax[tid], b = rmax[tid + s2]; rmax[tid] = a > b ? a : b; }
        __syncthreads();
    }
    unsigned int bidx = 0xFFFFFFFFu - (unsigned int)(rmax[0] & 0xFFFFFFFFull);
    int row = (int)(bidx >> 10), col = (int)(bidx & 1023);
    int r0 = row - 20; if (r0 < 0) r0 = 0; if (r0 > SS - 41) r0 = SS - 41;
    int c0 = col - 20; if (c0 < 0) c0 = 0; if (c0 > SS - 41) c0 = SS - 41;
    const float* p = psf + ((size_t)c << 20);
    float local = 0.0f;
    for (int i = tid; i < 1681; i += 256) {
        int rr = i / 41, cc = i - rr * 41;
        local += p[(size_t)(r0 + rr) * SS + c0 + cc];
    }
    red[tid] = local;
    __syncthreads();
    for (int s2 = 128; s2 > 0; s2 >>= 1) {
        if (tid < s2) red[tid] += red[tid + s2];
        __syncthreads();
    }
    float inv = 1.0f / red[0];
    for (int i = tid; i < 1681; i += 256) {
        int rr = i / 41, cc = i - rr * 41;
        out[c * 1681 + i] = p[(size_t)(r0 + rr) * SS + c0 + cc] * inv;
    }
}

// ---------------------------------------------------------------------------
extern "C" void kernel_launch(void* const* d_in, const int* in_sizes, int n_in,
                              void* d_out, int out_size, void* d_ws,
                              size_t ws_size, hipStream_t stream) {
    const float* lms = (const float*)d_in[0];
    const float* fuse = (const float*)d_in[1];
    char* ws = (char*)d_ws;
    float2* Zf = (float2*)ws;                                   // 64 MB: 8 planes
    float2* Wb = (float2*)(ws + ((size_t)64 << 20));            // 32 MB: 4 planes
    float* psf = (float*)ws;                                    // 32 MB, reuses Zf
    ull* bm = (ull*)(ws + ((size_t)33 << 20));                  // 64 KB, dead Zf region
    float* outp = (float*)d_out;

    // 1. fused blur + pack + forward row-FFT -> Zf[c][y][kx]
    blur_fft_kernel<<<8192, 256, 0, stream>>>(lms, fuse, Zf);
    // 2. fused col-FFT (strided, L3-backed) + Wiener + inverse-ky-FFT -> Wb[p][kx][y]
    fft2_wiener_kernel<<<2048, 256, 0, stream>>>(Zf, Wb);
    // 3. inverse kx-FFT (strided, L3-backed) + shift/threshold/split/block-argmax
    ifft_final_kernel<<<4096, 256, 0, stream>>>(Wb, psf, bm);
    // 4. argmax finish + crop/normalize
    crop_kernel<<<8, 256, 0, stream>>>(psf, bm, outp);
}

// Round 3
// 189.787 us; speedup vs baseline: 1.2661x; 1.0941x over previous
//
#include <hip/hip_runtime.h>
#include <math.h>

#define SS 1024
#define NC 8
#define BWD 170
#define THRESH 1e-4f

typedef unsigned long long ull;

__device__ __forceinline__ float2 cmul(float2 a, float2 b) {
    return make_float2(a.x * b.x - a.y * b.y, a.x * b.y + a.y * b.x);
}

// ---------------------------------------------------------------------------
// XOR bank swizzle for FFT LDS buffers: bijection on [0,1024), mixes bits 4-7
// into bits 0-3 so every Stockham write stage hits 16 distinct bank-pairs
// while stride-1 reads stay conflict-free.
// ---------------------------------------------------------------------------
#define XS(a) ((a) ^ (((a) >> 4) & 15))

// ---------------------------------------------------------------------------
// Pair-interleaved column map for Zf: column kx and its conjugate partner
// 1024-kx land in ADJACENT float2 slots, so the fft2 consumer reads both
// with one dense float4 per (y,m). Bijection on [0,1024):
//   0->0, 512->1, kx in [1,511] -> 2kx, kx in [513,1023] -> 2(1024-kx)+1.
// ---------------------------------------------------------------------------
__device__ __forceinline__ int cmap(int kx) {
    if (kx == 0) return 0;
    if (kx == 512) return 1;
    return (kx < 512) ? (kx << 1) : (((1024 - kx) << 1) | 1);
}

template <int DIR>
__device__ __forceinline__ void bfly4(const float2 v[4], float2 r[4]) {
    float2 a = v[0], b = v[1], c = v[2], d = v[3];
    float2 apc = make_float2(a.x + c.x, a.y + c.y);
    float2 amc = make_float2(a.x - c.x, a.y - c.y);
    float2 bpd = make_float2(b.x + d.x, b.y + d.y);
    float2 jb  = make_float2(-(b.y - d.y), b.x - d.x);   // i*(b-d)
    r[0] = make_float2(apc.x + bpd.x, apc.y + bpd.y);
    r[2] = make_float2(apc.x - bpd.x, apc.y - bpd.y);
    if (DIR == -1) {
        r[1] = make_float2(amc.x - jb.x, amc.y - jb.y);
        r[3] = make_float2(amc.x + jb.x, amc.y + jb.y);
    } else {
        r[1] = make_float2(amc.x + jb.x, amc.y + jb.y);
        r[3] = make_float2(amc.x - jb.x, amc.y - jb.y);
    }
}

// ---------------------------------------------------------------------------
// 1024-pt Stockham radix-4, register-resident ends, INLINE twiddles.
// Stages 0-3 via LDS (XS swizzle); stage 4 (twiddle-free, thread-local) in
// registers. sb=true runs SINGLE-BUFFERED (A==B): each stage becomes
// write -> sync -> read -> sync, so the same 8KB region is safely reused
// (costs 4 extra barriers; lets the caller drop the scratch buffer).
// On entry v[m] holds element (tid+256m); on exit v[r] = element tid+256r.
// ---------------------------------------------------------------------------
template <int DIR>
__device__ __forceinline__ void fft1024_reg(float2 v[4], float2* A, float2* B,
                                            int tid, bool sb) {
    float2* dst = A;
    float2* alt = B;
    #pragma unroll
    for (int t = 0; t < 4; ++t) {
        int s = 1 << (2 * t);
        int k = tid & ~(s - 1);
        float2 r[4];
        bfly4<DIR>(v, r);
        float rev = (float)k * (1.0f / 1024.0f);
        float2 w1 = make_float2(__builtin_amdgcn_cosf(rev),
                                (float)DIR * __builtin_amdgcn_sinf(rev));
        float2 w2 = cmul(w1, w1);
        float2 w3 = cmul(w2, w1);
        int base = tid + 3 * k;
        dst[XS(base)]         = r[0];
        dst[XS(base + s)]     = cmul(r[1], w1);
        dst[XS(base + 2 * s)] = cmul(r[2], w2);
        dst[XS(base + 3 * s)] = cmul(r[3], w3);
        __syncthreads();
        v[0] = dst[XS(tid)];
        v[1] = dst[XS(tid + 256)];
        v[2] = dst[XS(tid + 512)];
        v[3] = dst[XS(tid + 768)];
        if (sb) __syncthreads();
        float2* tmp = dst; dst = alt; alt = tmp;
    }
    float2 r[4];
    bfly4<DIR>(v, r);   // stage 4: twiddle-free, thread-local
    v[0] = r[0]; v[1] = r[1]; v[2] = r[2]; v[3] = r[3];
}

// LDS padding for the H-blur row buffers (float units, stride-4 reads)
#define PIDX(r) ((r) + ((r) >> 5))

// ---------------------------------------------------------------------------
// Fused blur + alpha blend + pack + forward row FFT. Block = (channel, row).
// XCD-band swizzle keeps the 7-row V-blur halo in one XCD's L2.
// V-blur in registers, H-blur via one LDS row, alpha blend,
// pack Z = lms_e + i*fuse_e into bufA (XS layout), FFT, store from registers
// into the PAIR-INTERLEAVED cmap layout (stride-2 per wave; the mirror wave
// of the same block fills the other half of each line -> L2 write-combines).
// ---------------------------------------------------------------------------
__global__ __launch_bounds__(256) void blur_fft_kernel(
        const float* __restrict__ lms, const float* __restrict__ fuse,
        float2* __restrict__ Zf) {
    __shared__ float2 bufA[1024];      // handoff + FFT ping-pong partner
    __shared__ float2 smemB2[1068];    // aliases: rowl/rowf floats, FFT buffer
    float* rowl = (float*)smemB2;      // PIDX(col+3), col -3..1026
    float* rowf = rowl + 1068;
    int tid = threadIdx.x;
    int g = blockIdx.x;
    int c = g >> 10;
    int y = (g & 7) * 128 + ((g >> 3) & 127);   // XCD band swizzle
    const float* L = lms + ((size_t)c << 20);
    const float* F = fuse + ((size_t)c << 20);
    int x0 = tid << 2;

    // Gaussian weights (sigma=1, ks=7)
    double e1 = exp(-0.5), e2 = exp(-2.0), e3 = exp(-4.5);
    double sm = 1.0 + 2.0 * (e1 + e2 + e3);
    float w[7] = { (float)(e3 / sm), (float)(e2 / sm), (float)(e1 / sm),
                   (float)(1.0 / sm),
                   (float)(e1 / sm), (float)(e2 / sm), (float)(e3 / sm) };

    bool rowInt = (y >= BWD) && (y <= SS - 1 - BWD);
    bool skipLoads = rowInt && (tid >= 45) && (tid <= 210);
    bool doH = !rowInt || (tid <= 43) || (tid >= 212);

    float4 cl, cf;
    if (skipLoads) {
        cl = *(const float4*)&L[((size_t)y << 10) + x0];
        cf = *(const float4*)&F[((size_t)y << 10) + x0];
    } else {
        float4 lv[7], fv[7];
        #pragma unroll
        for (int r = 0; r < 7; ++r) {
            int gy = y - 3 + r;
            if (gy >= 0 && gy < SS) {
                lv[r] = *(const float4*)&L[((size_t)gy << 10) + x0];
                fv[r] = *(const float4*)&F[((size_t)gy << 10) + x0];
            } else {
                lv[r] = make_float4(0.f, 0.f, 0.f, 0.f);
                fv[r] = make_float4(0.f, 0.f, 0.f, 0.f);
            }
        }
        cl = lv[3]; cf = fv[3];
        #pragma unroll
        for (int j = 0; j < 4; ++j) {
            float a = 0.f, b = 0.f;
            #pragma unroll
            for (int r = 0; r < 7; ++r) {
                a += w[r] * (&lv[r].x)[j];
                b += w[r] * (&fv[r].x)[j];
            }
            rowl[PIDX(3 + x0 + j)] = a;
            rowf[PIDX(3 + x0 + j)] = b;
        }
    }
    if (tid < 3) {
        rowl[PIDX(tid)] = 0.f; rowf[PIDX(tid)] = 0.f;
        rowl[PIDX(1027 + tid)] = 0.f; rowf[PIDX(1027 + tid)] = 0.f;
    }
    __syncthreads();

    float bl[4] = {0.f, 0.f, 0.f, 0.f}, bf[4] = {0.f, 0.f, 0.f, 0.f};
    if (doH) {
        #pragma unroll
        for (int k = 0; k < 4; ++k) {
            float a = 0.f, b = 0.f;
            #pragma unroll
            for (int j = 0; j < 7; ++j) {
                a += w[j] * rowl[PIDX(x0 + k + j)];
                b += w[j] * rowf[PIDX(x0 + k + j)];
            }
            bl[k] = a; bf[k] = b;
        }
    }
    int gyv = (y < BWD) ? y : ((SS - 1 - y) < BWD ? (SS - 1 - y) : -1);
    #pragma unroll
    for (int k = 0; k < 4; ++k) {
        int x = x0 + k;
        int gx = (x < BWD) ? x : ((SS - 1 - x) < BWD ? (SS - 1 - x) : -1);
        int m = gyv > gx ? gyv : gx;
        float a = (m >= 0) ? (float)m / (float)BWD : 1.0f;
        bufA[XS(x)] = make_float2(a * (&cl.x)[k] + (1.0f - a) * bl[k],
                                  a * (&cf.x)[k] + (1.0f - a) * bf[k]);
    }
    __syncthreads();   // bufA handoff ready; rowl/rowf reads done

    float2 v[4];
    #pragma unroll
    for (int m = 0; m < 4; ++m) v[m] = bufA[XS(tid + (m << 8))];
    fft1024_reg<-1>(v, smemB2, bufA, tid, false);

    float2* Zrow = Zf + (((size_t)c << 20) + ((size_t)y << 10));
    #pragma unroll
    for (int r = 0; r < 4; ++r) Zrow[cmap(tid + (r << 8))] = v[r];
}

// ---------------------------------------------------------------------------
// Fused second forward FFT + Wiener + first inverse FFT (along ky).
// Reads the pair-interleaved Zf: one float4 per (y,m) delivers BOTH columns
// u and 1024-u of a channel (dense 16B/lane; line traffic 4x lower than the
// strided-8B scheme). Chunked XCD swizzle co-locates line-sharing blocks.
// LDS = 4 result buffers ONLY (32KB -> 5 blocks/CU): forward FFTs ping-pong
// through not-yet-written resbuf slots (exec order 0,2,1,3; combo 3 runs
// single-buffered). 4 fwd FFTs, Wiener to registers, 2 inverse FFTs, store
// Wb[p][u][y] coalesced from registers.
// ---------------------------------------------------------------------------
__global__ __launch_bounds__(256) void fft2_wiener_kernel(
        const float2* __restrict__ Z, float2* __restrict__ Wb) {
    __shared__ float2 resbuf[4][1024];
    int tid = threadIdx.x;
    int p = blockIdx.x >> 9;          // channel pair 0..3
    int b0 = blockIdx.x & 511;
    int i = ((b0 & 7) << 6) | (b0 >> 3);   // chunked XCD swizzle (64/chunk)
    int rows[2];
    rows[0] = (i == 0) ? 0 : i;
    rows[1] = (i == 0) ? 512 : 1024 - i;
    bool selfp = (i == 0);
    int slot = (i == 0) ? 0 : (i << 1);

    const float2* Zp0 = Z + ((size_t)(2 * p) << 20);
    const float2* Zp1 = Z + ((size_t)(2 * p + 1) << 20);
    float4 q0[4], q1[4];
    #pragma unroll
    for (int m = 0; m < 4; ++m)
        q0[m] = *(const float4*)&Zp0[((size_t)(tid + (m << 8)) << 10) + slot];
    #pragma unroll
    for (int m = 0; m < 4; ++m)
        q1[m] = *(const float4*)&Zp1[((size_t)(tid + (m << 8)) << 10) + slot];

    float2 v[4];
    // combo 0 = (row0, ch0); scratch = resbuf[2] (dead until exec step 1)
    #pragma unroll
    for (int m = 0; m < 4; ++m) v[m] = make_float2(q0[m].x, q0[m].y);
    fft1024_reg<-1>(v, resbuf[2], resbuf[0], tid, false);
    #pragma unroll
    for (int r = 0; r < 4; ++r) resbuf[0][XS(tid + (r << 8))] = v[r];
    // combo 2 = (row1, ch0); scratch = resbuf[1]
    #pragma unroll
    for (int m = 0; m < 4; ++m) v[m] = make_float2(q0[m].z, q0[m].w);
    fft1024_reg<-1>(v, resbuf[1], resbuf[2], tid, false);
    #pragma unroll
    for (int r = 0; r < 4; ++r) resbuf[2][XS(tid + (r << 8))] = v[r];
    // combo 1 = (row0, ch1); scratch = resbuf[3]
    #pragma unroll
    for (int m = 0; m < 4; ++m) v[m] = make_float2(q1[m].x, q1[m].y);
    fft1024_reg<-1>(v, resbuf[3], resbuf[1], tid, false);
    #pragma unroll
    for (int r = 0; r < 4; ++r) resbuf[1][XS(tid + (r << 8))] = v[r];
    // combo 3 = (row1, ch1); all other buffers live -> single-buffered
    #pragma unroll
    for (int m = 0; m < 4; ++m) v[m] = make_float2(q1[m].z, q1[m].w);
    fft1024_reg<-1>(v, resbuf[3], resbuf[3], tid, true);
    #pragma unroll
    for (int r = 0; r < 4; ++r) resbuf[3][XS(tid + (r << 8))] = v[r];
    __syncthreads();   // all forward results visible

    // Wiener to registers
    float2 gout[2][4];
    #pragma unroll
    for (int o = 0; o < 2; ++o) {
        int u = rows[o];
        int po = selfp ? o : (1 - o);      // partner row's slot base
        float cu = __builtin_amdgcn_cosf((float)u * (1.0f / 1024.0f));
        float c2u = 2.0f * cu * cu - 1.0f;
        float hu = 2.0f + 2.0f * cu;
        #pragma unroll
        for (int j = 0; j < 4; ++j) {
            int vv = tid + (j << 8);
            int vn = (1024 - vv) & 1023;
            float cv = __builtin_amdgcn_cosf((float)vv * (1.0f / 1024.0f));
            float c2v = 2.0f * cv * cv - 1.0f;
            float hv = 2.0f + 2.0f * cv;
            float grad = (2.0f - 2.0f * c2v) * hu * hu +
                         (2.0f - 2.0f * c2u) * hv * hv;
            float regs = 5.0f + 5.0f * grad;
            float G0x, G0y, G1x, G1y;
            #pragma unroll
            for (int c = 0; c < 2; ++c) {
                float2 a = resbuf[o * 2 + c][XS(vv)];
                float2 b = resbuf[po * 2 + c][XS(vn)];
                float Lx = 0.5f * (a.x + b.x), Ly = 0.5f * (a.y - b.y);
                float Fx = 0.5f * (a.y + b.y), Fy = -0.5f * (a.x - b.x);
                float inv = 1.0f / (Fx * Fx + Fy * Fy + regs);
                float nx = (Fx * Lx + Fy * Ly) * inv;   // conj(F)*L
                float ny = (Fx * Ly - Fy * Lx) * inv;
                if (c == 0) { G0x = nx; G0y = ny; } else { G1x = nx; G1y = ny; }
            }
            gout[o][j] = make_float2(G0x - G1y, G0y + G1x);
        }
    }
    __syncthreads();   // all resbuf reads complete; buffers reusable

    // inverse FFT along ky for both owned rows; store from registers
    const float isc = 1.0f / 1024.0f;
    #pragma unroll
    for (int o = 0; o < 2; ++o) {
        float2 iv[4];
        #pragma unroll
        for (int j = 0; j < 4; ++j) iv[j] = gout[o][j];   // already tid+256j
        fft1024_reg<1>(iv, resbuf[1 + 2 * o], resbuf[2 * o], tid, false);
        float2* go = Wb + (((size_t)p << 20) + ((size_t)rows[o] << 10));
        #pragma unroll
        for (int r = 0; r < 4; ++r)
            go[tid + (r << 8)] = make_float2(iv[r].x * isc, iv[r].y * isc);
    }
}

// ---------------------------------------------------------------------------
// Final inverse pass: block handles TWO adjacent output rows (y0, y0+1) via
// dense float4 column loads of Wb[p][kx][y0..y0+1] (16B/lane/line, halves
// the strided-line traffic). Chunked XCD swizzle co-locates line-sharers.
// Register row FFT, fused 1/N scale + fftshift + threshold + split into two
// real psf planes + PER-WAVE argmax to private slots bm[ch*4096 + y*4 + wv]
// (no cross-wave reduce, no barriers outside the FFT).
// ---------------------------------------------------------------------------
__global__ __launch_bounds__(256) void ifft_final_kernel(
        const float2* __restrict__ Wd, float* __restrict__ psf,
        ull* __restrict__ bm) {
    __shared__ float2 bufA[1024];
    __shared__ float2 bufB[1024];
    int tid = threadIdx.x;
    int wv = tid >> 6;
    int p = blockIdx.x >> 9;           // grid 2048: 4 planes x 512
    int b0 = blockIdx.x & 511;
    int y0 = (((b0 & 7) << 6) | (b0 >> 3)) << 1;   // chunked swizzle, 2 rows
    const float2* g = Wd + (((size_t)p << 20) + y0);
    float4 q[4];
    #pragma unroll
    for (int m = 0; m < 4; ++m)
        q[m] = *(const float4*)&g[(size_t)(tid + (m << 8)) << 10];

    const float sc = 1.0f / 1024.0f;
    #pragma unroll
    for (int half = 0; half < 2; ++half) {
        int y = y0 + half;
        float2 v[4];
        #pragma unroll
        for (int m = 0; m < 4; ++m)
            v[m] = half ? make_float2(q[m].z, q[m].w)
                        : make_float2(q[m].x, q[m].y);
        fft1024_reg<1>(v, bufA, bufB, tid, false);  // internal barriers fence reuse

        int oy = (y + 512) & 1023;
        float* p0 = psf + (((size_t)(2 * p) << 20) + ((size_t)oy << 10));
        float* p1 = p0 + (1u << 20);
        ull e0 = 0, e1 = 0;
        #pragma unroll
        for (int r = 0; r < 4; ++r) {
            int k = tid + (r << 8);
            float re = v[r].x * sc; re = (re < THRESH) ? 0.0f : re;
            float im = v[r].y * sc; im = (im < THRESH) ? 0.0f : im;
            int ox = (k + 512) & 1023;
            p0[ox] = re;
            p1[ox] = im;
            unsigned int idx = ((unsigned int)oy << 10) | (unsigned int)ox;
            ull c0 = ((ull)__float_as_uint(re) << 32) | (ull)(0xFFFFFFFFu - idx);
            ull c1 = ((ull)__float_as_uint(im) << 32) | (ull)(0xFFFFFFFFu - idx);
            e0 = c0 > e0 ? c0 : e0;
            e1 = c1 > e1 ? c1 : e1;
        }
        #pragma unroll
        for (int off = 32; off > 0; off >>= 1) {
            ull o0 = __shfl_down(e0, off);
            ull o1 = __shfl_down(e1, off);
            e0 = o0 > e0 ? o0 : e0;
            e1 = o1 > e1 ? o1 : e1;
        }
        if ((tid & 63) == 0) {
            bm[((size_t)(2 * p) << 12) + (y << 2) + wv] = e0;
            bm[((size_t)(2 * p + 1) << 12) + (y << 2) + wv] = e1;
        }
    }
}

// ---------------------------------------------------------------------------
// Per-channel argmax finish (reduce 4096 per-wave maxima) + crop 41x41
// (dynamic_slice clamp semantics) + normalize. One block per channel.
// ---------------------------------------------------------------------------
__global__ __launch_bounds__(256) void crop_kernel(
        const float* __restrict__ psf, const ull* __restrict__ bm,
        float* __restrict__ out) {
    int c = blockIdx.x;
    __shared__ ull rmax[256];
    __shared__ float red[256];
    int tid = threadIdx.x;
    ull e = 0;
    for (int i = tid; i < 4096; i += 256) {
        ull v = bm[((size_t)c << 12) + i];
        e = v > e ? v : e;
    }
    rmax[tid] = e;
    __syncthreads();
    for (int s2 = 128; s2 > 0; s2 >>= 1) {
        if (tid < s2) { ull a = rmax[tid], b = rmax[tid + s2]; rmax[tid] = a > b ? a : b; }
        __syncthreads();
    }
    unsigned int bidx = 0xFFFFFFFFu - (unsigned int)(rmax[0] & 0xFFFFFFFFull);
    int row = (int)(bidx >> 10), col = (int)(bidx & 1023);
    int r0 = row - 20; if (r0 < 0) r0 = 0; if (r0 > SS - 41) r0 = SS - 41;
    int c0 = col - 20; if (c0 < 0) c0 = 0; if (c0 > SS - 41) c0 = SS - 41;
    const float* p = psf + ((size_t)c << 20);
    float local = 0.0f;
    for (int i = tid; i < 1681; i += 256) {
        int rr = i / 41, cc = i - rr * 41;
        local += p[(size_t)(r0 + rr) * SS + c0 + cc];
    }
    red[tid] = local;
    __syncthreads();
    for (int s2 = 128; s2 > 0; s2 >>= 1) {
        if (tid < s2) red[tid] += red[tid + s2];
        __syncthreads();
    }
    float inv = 1.0f / red[0];
    for (int i = tid; i < 1681; i += 256) {
        int rr = i / 41, cc = i - rr * 41;
        out[c * 1681 + i] = p[(size_t)(r0 + rr) * SS + c0 + cc] * inv;
    }
}

// ---------------------------------------------------------------------------
extern "C" void kernel_launch(void* const* d_in, const int* in_sizes, int n_in,
                              void* d_out, int out_size, void* d_ws,
                              size_t ws_size, hipStream_t stream) {
    const float* lms = (const float*)d_in[0];
    const float* fuse = (const float*)d_in[1];
    char* ws = (char*)d_ws;
    float2* Zf = (float2*)ws;                                   // 64 MB: 8 planes
    float2* Wb = (float2*)(ws + ((size_t)64 << 20));            // 32 MB: 4 planes
    float* psf = (float*)ws;                                    // 32 MB, reuses Zf
    ull* bm = (ull*)(ws + ((size_t)33 << 20));                  // 256 KB, dead Zf region
    float* outp = (float*)d_out;

    // 1. fused blur + pack + forward row-FFT -> Zf[c][y][cmap(kx)]
    blur_fft_kernel<<<8192, 256, 0, stream>>>(lms, fuse, Zf);
    // 2. fused col-FFT (dense pair reads) + Wiener + inverse-ky-FFT -> Wb[p][kx][y]
    fft2_wiener_kernel<<<2048, 256, 0, stream>>>(Zf, Wb);
    // 3. inverse kx-FFT (2 rows/block, float4 column reads) + shift/threshold/argmax
    ifft_final_kernel<<<2048, 256, 0, stream>>>(Wb, psf, bm);
    // 4. argmax finish + crop/normalize
    crop_kernel<<<8, 256, 0, stream>>>(psf, bm, outp);
}